// Round 5
// baseline (858.714 us; speedup 1.0000x reference)
//
#include <hip/hip_runtime.h>
#include <hip/hip_fp16.h>
#include <math.h>

#define NEG_SLOPE 0.2f

__device__ __forceinline__ float lrelu(float x) { return x >= 0.f ? x : NEG_SLOPE * x; }

// ---------------- CSR build (by dst) ----------------

__global__ void hist_kernel(const int* __restrict__ dst, int E, int* __restrict__ cnt) {
    int i = blockIdx.x * blockDim.x + threadIdx.x;
    int stride = gridDim.x * blockDim.x;
    for (; i < E; i += stride) atomicAdd(&cnt[dst[i]], 1);
}

// wave-scan allocation: 1 atomic per wave instead of 1 per node
__global__ void alloc_kernel(const int* __restrict__ cnt, int N,
                             int* __restrict__ start, int* __restrict__ total) {
    int i = blockIdx.x * blockDim.x + threadIdx.x;
    int lane = threadIdx.x & 63;
    int v = (i < N) ? cnt[i] + 1 : 0;   // +1 self loop
    int incl = v;
#pragma unroll
    for (int d = 1; d < 64; d <<= 1) {
        int t = __shfl_up(incl, d);
        if (lane >= d) incl += t;
    }
    int wtot = __shfl(incl, 63);
    int base = 0;
    if (lane == 0) base = atomicAdd(total, wtot);
    base = __shfl(base, 0);
    if (i < N) start[i] = base + incl - v;
}

__global__ void scatter_kernel(const int* __restrict__ src, const int* __restrict__ dst,
                               int E, int N, const int* __restrict__ start,
                               int* __restrict__ fill, int* __restrict__ col) {
    int i = blockIdx.x * blockDim.x + threadIdx.x;
    int stride = gridDim.x * blockDim.x;
    int tot = E + N;
    for (; i < tot; i += stride) {
        int s, d;
        if (i < E) { s = src[i]; d = dst[i]; }
        else       { s = i - E; d = s; }       // self loop
        int p = start[d] + atomicAdd(&fill[d], 1);
        col[p] = s;
    }
}

// ---------------- Register-tiled GEMM (M x 128 @ 128 x 128) + alpha epilogue ----
// 256 threads -> 64 rows x 128 cols. Thread (tx,ty) owns 8x4 accumulators.
// Feature output written as fp16 (halves aggregation gather traffic).

template <int H>
__global__ __launch_bounds__(256) void gemm_tiled_kernel(
    const float* __restrict__ X, const float* __restrict__ W,
    const float* __restrict__ avs, const float* __restrict__ avd,
    __half* __restrict__ HmH, float* __restrict__ As, float* __restrict__ Ad, int N) {
    __shared__ float Xs[32][64];    // [k][row]
    __shared__ float Ws[32][128];   // [k][col]
    const int tid = threadIdx.x;
    const int tx = tid & 31;
    const int ty = tid >> 5;
    const int row0 = blockIdx.x * 64;

    float acc[8][4];
#pragma unroll
    for (int r = 0; r < 8; ++r)
#pragma unroll
        for (int c = 0; c < 4; ++c) acc[r][c] = 0.f;

    const float4 as_v = *(const float4*)(avs + tx * 4);
    const float4 ad_v = *(const float4*)(avd + tx * 4);

    for (int k0 = 0; k0 < 128; k0 += 32) {
#pragma unroll
        for (int i = 0; i < 2; ++i) {
            int c = tid + 256 * i;
            int r = c & 63;
            int kc = (c >> 6) << 2;
            int grow = row0 + r;
            float4 v = make_float4(0.f, 0.f, 0.f, 0.f);
            if (grow < N) v = *(const float4*)(X + (size_t)grow * 128 + k0 + kc);
            Xs[kc + 0][r] = v.x;
            Xs[kc + 1][r] = v.y;
            Xs[kc + 2][r] = v.z;
            Xs[kc + 3][r] = v.w;
        }
#pragma unroll
        for (int i = 0; i < 4; ++i) {
            int c = tid + 256 * i;
            int kk = c >> 5;
            int cc = (c & 31) << 2;
            *(float4*)(&Ws[kk][cc]) = *(const float4*)(W + (size_t)(k0 + kk) * 128 + cc);
        }
        __syncthreads();
#pragma unroll
        for (int k = 0; k < 32; ++k) {
            float4 xa = *(const float4*)(&Xs[k][ty * 8]);
            float4 xb = *(const float4*)(&Xs[k][ty * 8 + 4]);
            float4 wv = *(const float4*)(&Ws[k][tx * 4]);
            float xf[8] = {xa.x, xa.y, xa.z, xa.w, xb.x, xb.y, xb.z, xb.w};
            float wf[4] = {wv.x, wv.y, wv.z, wv.w};
#pragma unroll
            for (int r = 0; r < 8; ++r)
#pragma unroll
                for (int c = 0; c < 4; ++c) acc[r][c] += xf[r] * wf[c];
        }
        __syncthreads();
    }

#pragma unroll
    for (int r = 0; r < 8; ++r) {
        int grow = row0 + ty * 8 + r;
        if (grow >= N) continue;   // uniform across each 32-lane half
        float4 o = make_float4(acc[r][0], acc[r][1], acc[r][2], acc[r][3]);
        __half2* o2 = (__half2*)(HmH + (size_t)grow * 128 + tx * 4);
        o2[0] = __floats2half2_rn(o.x, o.y);
        o2[1] = __floats2half2_rn(o.z, o.w);
        float ps = o.x * as_v.x + o.y * as_v.y + o.z * as_v.z + o.w * as_v.w;
        float pd = o.x * ad_v.x + o.y * ad_v.y + o.z * ad_v.z + o.w * ad_v.w;
        if (H == 4) {
            ps += __shfl_xor(ps, 1); ps += __shfl_xor(ps, 2); ps += __shfl_xor(ps, 4);
            pd += __shfl_xor(pd, 1); pd += __shfl_xor(pd, 2); pd += __shfl_xor(pd, 4);
            if ((tx & 7) == 0) {
                int h = tx >> 3;
                As[(size_t)grow * 4 + h] = ps;
                Ad[(size_t)grow * 4 + h] = pd;
            }
        } else {
#pragma unroll
            for (int m = 1; m <= 16; m <<= 1) {
                ps += __shfl_xor(ps, m);
                pd += __shfl_xor(pd, m);
            }
            if (tx == 0) { As[grow] = ps; Ad[grow] = pd; }
        }
    }
}

// ---------------- Aggregation layer 1 (H=4, +bias, ELU) ----------------
// One wave per dst node. lane l owns channels 2l, 2l+1 (head = lane>>4).
// P4[j]: per-edge scratch; pass1 stores e, pass2 stores p=exp(e-m).

__global__ __launch_bounds__(256) void agg1_kernel(
    const __half2* __restrict__ Hm2, const int* __restrict__ col,
    const int* __restrict__ start, const int* __restrict__ cnt,
    const float4* __restrict__ As4, const float4* __restrict__ Ad4,
    const float* __restrict__ bias, float4* __restrict__ P4,
    float* __restrict__ G, int N) {
    const int lane = threadIdx.x & 63;
    const int node = (blockIdx.x * 256 + threadIdx.x) >> 6;
    if (node >= N) return;
    const int s = start[node];
    const int e_end = s + cnt[node] + 1;
    const float4 ad = Ad4[node];

    // pass 1: e = lrelu(As[u]+Ad[node]); store; running max (lane-parallel)
    float m0 = -INFINITY, m1 = -INFINITY, m2 = -INFINITY, m3 = -INFINITY;
    for (int j = s + lane; j < e_end; j += 64) {
        float4 a = As4[col[j]];
        float e0 = lrelu(a.x + ad.x), e1 = lrelu(a.y + ad.y);
        float e2 = lrelu(a.z + ad.z), e3 = lrelu(a.w + ad.w);
        P4[j] = make_float4(e0, e1, e2, e3);
        m0 = fmaxf(m0, e0); m1 = fmaxf(m1, e1);
        m2 = fmaxf(m2, e2); m3 = fmaxf(m3, e3);
    }
#pragma unroll
    for (int m = 32; m >= 1; m >>= 1) {
        m0 = fmaxf(m0, __shfl_xor(m0, m));
        m1 = fmaxf(m1, __shfl_xor(m1, m));
        m2 = fmaxf(m2, __shfl_xor(m2, m));
        m3 = fmaxf(m3, __shfl_xor(m3, m));
    }
    // pass 2: p = exp(e-m); store; denom (sequential reads)
    float d0 = 0.f, d1 = 0.f, d2 = 0.f, d3 = 0.f;
    for (int j = s + lane; j < e_end; j += 64) {
        float4 e = P4[j];
        float p0 = __expf(e.x - m0), p1 = __expf(e.y - m1);
        float p2 = __expf(e.z - m2), p3 = __expf(e.w - m3);
        P4[j] = make_float4(p0, p1, p2, p3);
        d0 += p0; d1 += p1; d2 += p2; d3 += p3;
    }
#pragma unroll
    for (int m = 32; m >= 1; m >>= 1) {
        d0 += __shfl_xor(d0, m);
        d1 += __shfl_xor(d1, m);
        d2 += __shfl_xor(d2, m);
        d3 += __shfl_xor(d3, m);
    }
    const float iv0 = 1.f / (d0 + 1e-16f), iv1 = 1.f / (d1 + 1e-16f);
    const float iv2 = 1.f / (d2 + 1e-16f), iv3 = 1.f / (d3 + 1e-16f);

    const int hsel = lane >> 4;   // head of channels 2l, 2l+1
    const float ivh = hsel == 0 ? iv0 : hsel == 1 ? iv1 : hsel == 2 ? iv2 : iv3;

    // pass 3: serial edge loop; uniform p load + one coalesced half2 gather
    float acc0 = 0.f, acc1 = 0.f;
    for (int j = s; j < e_end; ++j) {
        int u = col[j];
        float4 p = P4[j];
        float ph = hsel == 0 ? p.x : hsel == 1 ? p.y : hsel == 2 ? p.z : p.w;
        float w = ph * ivh;
        float2 hv = __half22float2(Hm2[(size_t)u * 64 + lane]);
        acc0 += w * hv.x;
        acc1 += w * hv.y;
    }
    float2 bv = ((const float2*)bias)[lane];
    float v0 = acc0 + bv.x, v1 = acc1 + bv.y;
    ((float2*)(G + (size_t)node * 128))[lane] =
        make_float2(v0 > 0.f ? v0 : expm1f(v0), v1 > 0.f ? v1 : expm1f(v1));
}

// ---------------- Aggregation layer 2 (H=1, +bias) ----------------

__global__ __launch_bounds__(256) void agg2_kernel(
    const __half2* __restrict__ Hm2, const int* __restrict__ col,
    const int* __restrict__ start, const int* __restrict__ cnt,
    const float* __restrict__ As, const float* __restrict__ Ad,
    const float* __restrict__ bias, float* __restrict__ P,
    float* __restrict__ Out, int N) {
    const int lane = threadIdx.x & 63;
    const int node = (blockIdx.x * 256 + threadIdx.x) >> 6;
    if (node >= N) return;
    const int s = start[node];
    const int e_end = s + cnt[node] + 1;
    const float ad = Ad[node];

    float mx = -INFINITY;
    for (int j = s + lane; j < e_end; j += 64) {
        float e = lrelu(As[col[j]] + ad);
        P[j] = e;
        mx = fmaxf(mx, e);
    }
#pragma unroll
    for (int m = 32; m >= 1; m >>= 1) mx = fmaxf(mx, __shfl_xor(mx, m));

    float dsum = 0.f;
    for (int j = s + lane; j < e_end; j += 64) {
        float p = __expf(P[j] - mx);
        P[j] = p;
        dsum += p;
    }
#pragma unroll
    for (int m = 32; m >= 1; m >>= 1) dsum += __shfl_xor(dsum, m);
    const float iv = 1.f / (dsum + 1e-16f);

    float acc0 = 0.f, acc1 = 0.f;
    for (int j = s; j < e_end; ++j) {
        int u = col[j];
        float w = P[j] * iv;
        float2 hv = __half22float2(Hm2[(size_t)u * 64 + lane]);
        acc0 += w * hv.x;
        acc1 += w * hv.y;
    }
    float2 bv = ((const float2*)bias)[lane];
    ((float2*)(Out + (size_t)node * 128))[lane] = make_float2(acc0 + bv.x, acc1 + bv.y);
}

// ---------------- launch ----------------

static inline size_t align256(size_t x) { return (x + 255) & ~(size_t)255; }

extern "C" void kernel_launch(void* const* d_in, const int* in_sizes, int n_in,
                              void* d_out, int out_size, void* d_ws, size_t ws_size,
                              hipStream_t stream) {
    const float* x = (const float*)d_in[0];
    const int* edge_index = (const int*)d_in[1];
    const float* W1 = (const float*)d_in[2];
    const float* a_src1 = (const float*)d_in[3];
    const float* a_dst1 = (const float*)d_in[4];
    const float* b1 = (const float*)d_in[5];
    const float* W2 = (const float*)d_in[6];
    const float* a_src2 = (const float*)d_in[7];
    const float* a_dst2 = (const float*)d_in[8];
    const float* b2 = (const float*)d_in[9];

    const int N = in_sizes[0] / 128;
    const int E = in_sizes[1] / 2;
    const int* src = edge_index;
    const int* dst = edge_index + E;

    // workspace layout (~65 MB)
    char* ws = (char*)d_ws;
    size_t off = 0;
    int* cnt = (int*)(ws + off);   off += align256((size_t)N * 4);
    int* fill = (int*)(ws + off);  off += align256((size_t)N * 4);
    int* total = (int*)(ws + off); off += 256;
    size_t zero_bytes = off;       // cnt + fill + total must be zeroed
    int* start = (int*)(ws + off); off += align256((size_t)N * 4);
    int* col = (int*)(ws + off);   off += align256((size_t)(E + N) * 4);
    float* As1 = (float*)(ws + off); off += align256((size_t)N * 16);
    float* Ad1 = (float*)(ws + off); off += align256((size_t)N * 16);
    float* As2 = (float*)(ws + off); off += align256((size_t)N * 4);
    float* Ad2 = (float*)(ws + off); off += align256((size_t)N * 4);
    __half* HmH = (__half*)(ws + off); off += align256((size_t)N * 128 * 2); // h1, then h2 (fp16)
    float* Pbuf = (float*)(ws + off);  off += align256((size_t)(E + N) * 16); // per-edge scratch
    float* bufB = (float*)d_out;   // g1 = elu(out1); overwritten by agg2 at the end
    (void)ws_size;

    hipMemsetAsync(d_ws, 0, zero_bytes, stream);

    // CSR build
    hist_kernel<<<2048, 256, 0, stream>>>(dst, E, cnt);
    alloc_kernel<<<(N + 255) / 256, 256, 0, stream>>>(cnt, N, start, total);
    scatter_kernel<<<2048, 256, 0, stream>>>(src, dst, E, N, start, fill, col);

    const int gtiles = (N + 63) / 64;

    // layer 1
    gemm_tiled_kernel<4><<<gtiles, 256, 0, stream>>>(x, W1, a_src1, a_dst1, HmH, As1, Ad1, N);
    agg1_kernel<<<(N + 3) / 4, 256, 0, stream>>>((const __half2*)HmH, col, start, cnt,
                                                 (const float4*)As1, (const float4*)Ad1,
                                                 b1, (float4*)Pbuf, bufB, N);

    // layer 2 (h2 reuses HmH; gemm2 reads g1 from d_out, agg2 then overwrites d_out)
    gemm_tiled_kernel<1><<<gtiles, 256, 0, stream>>>(bufB, W2, a_src2, a_dst2, HmH, As2, Ad2, N);
    agg2_kernel<<<(N + 3) / 4, 256, 0, stream>>>((const __half2*)HmH, col, start, cnt,
                                                 As2, Ad2, b2, Pbuf, (float*)d_out, N);
}

// Round 6
// 606.738 us; speedup vs baseline: 1.4153x; 1.4153x over previous
//
#include <hip/hip_runtime.h>
#include <hip/hip_fp16.h>
#include <math.h>

#define NEG_SLOPE 0.2f

__device__ __forceinline__ float lrelu(float x) { return x >= 0.f ? x : NEG_SLOPE * x; }

// ---------------- CSR build (by dst) ----------------

__global__ void hist_kernel(const int* __restrict__ dst, int E, int* __restrict__ cnt) {
    int i = blockIdx.x * blockDim.x + threadIdx.x;
    int stride = gridDim.x * blockDim.x;
    for (; i < E; i += stride) atomicAdd(&cnt[dst[i]], 1);
}

// wave-scan allocation: 1 atomic per wave instead of 1 per node
__global__ void alloc_kernel(const int* __restrict__ cnt, int N,
                             int* __restrict__ start, int* __restrict__ total) {
    int i = blockIdx.x * blockDim.x + threadIdx.x;
    int lane = threadIdx.x & 63;
    int v = (i < N) ? cnt[i] + 1 : 0;   // +1 self loop
    int incl = v;
#pragma unroll
    for (int d = 1; d < 64; d <<= 1) {
        int t = __shfl_up(incl, d);
        if (lane >= d) incl += t;
    }
    int wtot = __shfl(incl, 63);
    int base = 0;
    if (lane == 0) base = atomicAdd(total, wtot);
    base = __shfl(base, 0);
    if (i < N) start[i] = base + incl - v;
}

__global__ void scatter_kernel(const int* __restrict__ src, const int* __restrict__ dst,
                               int E, int N, const int* __restrict__ start,
                               int* __restrict__ fill, int* __restrict__ col) {
    int i = blockIdx.x * blockDim.x + threadIdx.x;
    int stride = gridDim.x * blockDim.x;
    int tot = E + N;
    for (; i < tot; i += stride) {
        int s, d;
        if (i < E) { s = src[i]; d = dst[i]; }
        else       { s = i - E; d = s; }       // self loop
        int p = start[d] + atomicAdd(&fill[d], 1);
        col[p] = s;
    }
}

// ---------------- Register-tiled GEMM (M x 128 @ 128 x 128) + alpha epilogue ----
// 256 threads -> 64 rows x 128 cols. Thread (tx,ty) owns 8x4 accumulators.
// Feature output written as fp16 (halves aggregation gather traffic).

template <int H>
__global__ __launch_bounds__(256) void gemm_tiled_kernel(
    const float* __restrict__ X, const float* __restrict__ W,
    const float* __restrict__ avs, const float* __restrict__ avd,
    __half* __restrict__ HmH, float* __restrict__ As, float* __restrict__ Ad, int N) {
    __shared__ float Xs[32][64];    // [k][row]
    __shared__ float Ws[32][128];   // [k][col]
    const int tid = threadIdx.x;
    const int tx = tid & 31;
    const int ty = tid >> 5;
    const int row0 = blockIdx.x * 64;

    float acc[8][4];
#pragma unroll
    for (int r = 0; r < 8; ++r)
#pragma unroll
        for (int c = 0; c < 4; ++c) acc[r][c] = 0.f;

    const float4 as_v = *(const float4*)(avs + tx * 4);
    const float4 ad_v = *(const float4*)(avd + tx * 4);

    for (int k0 = 0; k0 < 128; k0 += 32) {
#pragma unroll
        for (int i = 0; i < 2; ++i) {
            int c = tid + 256 * i;
            int r = c & 63;
            int kc = (c >> 6) << 2;
            int grow = row0 + r;
            float4 v = make_float4(0.f, 0.f, 0.f, 0.f);
            if (grow < N) v = *(const float4*)(X + (size_t)grow * 128 + k0 + kc);
            Xs[kc + 0][r] = v.x;
            Xs[kc + 1][r] = v.y;
            Xs[kc + 2][r] = v.z;
            Xs[kc + 3][r] = v.w;
        }
#pragma unroll
        for (int i = 0; i < 4; ++i) {
            int c = tid + 256 * i;
            int kk = c >> 5;
            int cc = (c & 31) << 2;
            *(float4*)(&Ws[kk][cc]) = *(const float4*)(W + (size_t)(k0 + kk) * 128 + cc);
        }
        __syncthreads();
#pragma unroll
        for (int k = 0; k < 32; ++k) {
            float4 xa = *(const float4*)(&Xs[k][ty * 8]);
            float4 xb = *(const float4*)(&Xs[k][ty * 8 + 4]);
            float4 wv = *(const float4*)(&Ws[k][tx * 4]);
            float xf[8] = {xa.x, xa.y, xa.z, xa.w, xb.x, xb.y, xb.z, xb.w};
            float wf[4] = {wv.x, wv.y, wv.z, wv.w};
#pragma unroll
            for (int r = 0; r < 8; ++r)
#pragma unroll
                for (int c = 0; c < 4; ++c) acc[r][c] += xf[r] * wf[c];
        }
        __syncthreads();
    }

#pragma unroll
    for (int r = 0; r < 8; ++r) {
        int grow = row0 + ty * 8 + r;
        if (grow >= N) continue;   // uniform across each 32-lane half
        float4 o = make_float4(acc[r][0], acc[r][1], acc[r][2], acc[r][3]);
        __half2* o2 = (__half2*)(HmH + (size_t)grow * 128 + tx * 4);
        o2[0] = __floats2half2_rn(o.x, o.y);
        o2[1] = __floats2half2_rn(o.z, o.w);
        float ps = o.x * as_v.x + o.y * as_v.y + o.z * as_v.z + o.w * as_v.w;
        float pd = o.x * ad_v.x + o.y * ad_v.y + o.z * ad_v.z + o.w * ad_v.w;
        if (H == 4) {
            ps += __shfl_xor(ps, 1); ps += __shfl_xor(ps, 2); ps += __shfl_xor(ps, 4);
            pd += __shfl_xor(pd, 1); pd += __shfl_xor(pd, 2); pd += __shfl_xor(pd, 4);
            if ((tx & 7) == 0) {
                int h = tx >> 3;
                As[(size_t)grow * 4 + h] = ps;
                Ad[(size_t)grow * 4 + h] = pd;
            }
        } else {
#pragma unroll
            for (int m = 1; m <= 16; m <<= 1) {
                ps += __shfl_xor(ps, m);
                pd += __shfl_xor(pd, m);
            }
            if (tx == 0) { As[grow] = ps; Ad[grow] = pd; }
        }
    }
}

// ---------------- Fused aggregation layer 1 (H=4, +bias, ELU) ----------------
// One wave per dst node. Lanes = 4 edge slots (qid=lane>>4) x 16 channel
// groups (l15=lane&15; channels 8*l15..8*l15+7; head=l15>>2).
// Softmax without max-subtraction (logits O(+-6), exp safe in f32); the
// normalization is linear so it is applied once after accumulation.

__global__ __launch_bounds__(256) void agg1_kernel(
    const float4* __restrict__ Hm4,     // fp16 feature rows viewed as 16 x float4
    const int* __restrict__ col,
    const int* __restrict__ start, const int* __restrict__ cnt,
    const float4* __restrict__ As4, const float4* __restrict__ Ad4,
    const float* __restrict__ bias, float* __restrict__ G, int N) {
    const int lane = threadIdx.x & 63;
    const int node = (blockIdx.x * 256 + threadIdx.x) >> 6;
    if (node >= N) return;
    const int qid = lane >> 4;
    const int l15 = lane & 15;
    const int head = l15 >> 2;
    const int s = start[node];
    const int e_end = s + cnt[node] + 1;
    const float4 ad4 = Ad4[node];
    const float adh = head == 0 ? ad4.x : head == 1 ? ad4.y : head == 2 ? ad4.z : ad4.w;

    float acc[8];
#pragma unroll
    for (int c = 0; c < 8; ++c) acc[c] = 0.f;
    float dacc = 0.f;

    for (int j = s; j < e_end; j += 4) {
        const int jj = j + qid;
        const bool act = jj < e_end;
        const int u = act ? col[jj] : 0;
        const float4 a4 = As4[u];
        const float ah = head == 0 ? a4.x : head == 1 ? a4.y : head == 2 ? a4.z : a4.w;
        const float p = act ? __expf(lrelu(ah + adh)) : 0.f;
        dacc += p;
        const float4 hv = Hm4[(size_t)u * 16 + l15];
        const __half2* h2 = (const __half2*)&hv;
        const float2 f0 = __half22float2(h2[0]);
        const float2 f1 = __half22float2(h2[1]);
        const float2 f2 = __half22float2(h2[2]);
        const float2 f3 = __half22float2(h2[3]);
        acc[0] += p * f0.x; acc[1] += p * f0.y;
        acc[2] += p * f1.x; acc[3] += p * f1.y;
        acc[4] += p * f2.x; acc[5] += p * f2.y;
        acc[6] += p * f3.x; acc[7] += p * f3.y;
    }

    // per-head denom: lanes sharing a head are {l15 in 4h..4h+3} x {4 qids};
    // each edge's p appears in 4 lanes -> scale by 1/4.
    dacc += __shfl_xor(dacc, 1);
    dacc += __shfl_xor(dacc, 2);
    dacc += __shfl_xor(dacc, 16);
    dacc += __shfl_xor(dacc, 32);
    const float iv = 1.f / (dacc * 0.25f + 1e-16f);

    // combine the 4 edge slots' partial feature sums
#pragma unroll
    for (int c = 0; c < 8; ++c) {
        acc[c] += __shfl_xor(acc[c], 16);
        acc[c] += __shfl_xor(acc[c], 32);
    }

    if (qid == 0) {
        const float4 b0 = ((const float4*)bias)[l15 * 2];
        const float4 b1 = ((const float4*)bias)[l15 * 2 + 1];
        float o[8];
        o[0] = acc[0] * iv + b0.x; o[1] = acc[1] * iv + b0.y;
        o[2] = acc[2] * iv + b0.z; o[3] = acc[3] * iv + b0.w;
        o[4] = acc[4] * iv + b1.x; o[5] = acc[5] * iv + b1.y;
        o[6] = acc[6] * iv + b1.z; o[7] = acc[7] * iv + b1.w;
#pragma unroll
        for (int c = 0; c < 8; ++c) o[c] = o[c] > 0.f ? o[c] : expm1f(o[c]);
        float4* dst = (float4*)(G + (size_t)node * 128 + l15 * 8);
        dst[0] = make_float4(o[0], o[1], o[2], o[3]);
        dst[1] = make_float4(o[4], o[5], o[6], o[7]);
    }
}

// ---------------- Fused aggregation layer 2 (H=1, +bias) ----------------

__global__ __launch_bounds__(256) void agg2_kernel(
    const float4* __restrict__ Hm4, const int* __restrict__ col,
    const int* __restrict__ start, const int* __restrict__ cnt,
    const float* __restrict__ As, const float* __restrict__ Ad,
    const float* __restrict__ bias, float* __restrict__ Out, int N) {
    const int lane = threadIdx.x & 63;
    const int node = (blockIdx.x * 256 + threadIdx.x) >> 6;
    if (node >= N) return;
    const int qid = lane >> 4;
    const int l15 = lane & 15;
    const int s = start[node];
    const int e_end = s + cnt[node] + 1;
    const float adh = Ad[node];

    float acc[8];
#pragma unroll
    for (int c = 0; c < 8; ++c) acc[c] = 0.f;
    float dacc = 0.f;

    for (int j = s; j < e_end; j += 4) {
        const int jj = j + qid;
        const bool act = jj < e_end;
        const int u = act ? col[jj] : 0;
        const float a = As[u];
        const float p = act ? __expf(lrelu(a + adh)) : 0.f;
        dacc += p;
        const float4 hv = Hm4[(size_t)u * 16 + l15];
        const __half2* h2 = (const __half2*)&hv;
        const float2 f0 = __half22float2(h2[0]);
        const float2 f1 = __half22float2(h2[1]);
        const float2 f2 = __half22float2(h2[2]);
        const float2 f3 = __half22float2(h2[3]);
        acc[0] += p * f0.x; acc[1] += p * f0.y;
        acc[2] += p * f1.x; acc[3] += p * f1.y;
        acc[4] += p * f2.x; acc[5] += p * f2.y;
        acc[6] += p * f3.x; acc[7] += p * f3.y;
    }

    // denom: each edge's p appears in 16 lanes -> scale by 1/16
#pragma unroll
    for (int m = 1; m <= 32; m <<= 1) dacc += __shfl_xor(dacc, m);
    const float iv = 1.f / (dacc * 0.0625f + 1e-16f);

#pragma unroll
    for (int c = 0; c < 8; ++c) {
        acc[c] += __shfl_xor(acc[c], 16);
        acc[c] += __shfl_xor(acc[c], 32);
    }

    if (qid == 0) {
        const float4 b0 = ((const float4*)bias)[l15 * 2];
        const float4 b1 = ((const float4*)bias)[l15 * 2 + 1];
        float4* dst = (float4*)(Out + (size_t)node * 128 + l15 * 8);
        dst[0] = make_float4(acc[0] * iv + b0.x, acc[1] * iv + b0.y,
                             acc[2] * iv + b0.z, acc[3] * iv + b0.w);
        dst[1] = make_float4(acc[4] * iv + b1.x, acc[5] * iv + b1.y,
                             acc[6] * iv + b1.z, acc[7] * iv + b1.w);
    }
}

// ---------------- launch ----------------

static inline size_t align256(size_t x) { return (x + 255) & ~(size_t)255; }

extern "C" void kernel_launch(void* const* d_in, const int* in_sizes, int n_in,
                              void* d_out, int out_size, void* d_ws, size_t ws_size,
                              hipStream_t stream) {
    const float* x = (const float*)d_in[0];
    const int* edge_index = (const int*)d_in[1];
    const float* W1 = (const float*)d_in[2];
    const float* a_src1 = (const float*)d_in[3];
    const float* a_dst1 = (const float*)d_in[4];
    const float* b1 = (const float*)d_in[5];
    const float* W2 = (const float*)d_in[6];
    const float* a_src2 = (const float*)d_in[7];
    const float* a_dst2 = (const float*)d_in[8];
    const float* b2 = (const float*)d_in[9];

    const int N = in_sizes[0] / 128;
    const int E = in_sizes[1] / 2;
    const int* src = edge_index;
    const int* dst = edge_index + E;

    // workspace layout (~38 MB)
    char* ws = (char*)d_ws;
    size_t off = 0;
    int* cnt = (int*)(ws + off);   off += align256((size_t)N * 4);
    int* fill = (int*)(ws + off);  off += align256((size_t)N * 4);
    int* total = (int*)(ws + off); off += 256;
    size_t zero_bytes = off;       // cnt + fill + total must be zeroed
    int* start = (int*)(ws + off); off += align256((size_t)N * 4);
    int* col = (int*)(ws + off);   off += align256((size_t)(E + N) * 4);
    float* As1 = (float*)(ws + off); off += align256((size_t)N * 16);
    float* Ad1 = (float*)(ws + off); off += align256((size_t)N * 16);
    float* As2 = (float*)(ws + off); off += align256((size_t)N * 4);
    float* Ad2 = (float*)(ws + off); off += align256((size_t)N * 4);
    __half* HmH = (__half*)(ws + off); off += align256((size_t)N * 128 * 2); // h1, then h2 (fp16)
    float* bufB = (float*)d_out;   // g1 = elu(out1); overwritten by agg2 at the end
    (void)ws_size;

    hipMemsetAsync(d_ws, 0, zero_bytes, stream);

    // CSR build
    hist_kernel<<<2048, 256, 0, stream>>>(dst, E, cnt);
    alloc_kernel<<<(N + 255) / 256, 256, 0, stream>>>(cnt, N, start, total);
    scatter_kernel<<<2048, 256, 0, stream>>>(src, dst, E, N, start, fill, col);

    const int gtiles = (N + 63) / 64;

    // layer 1
    gemm_tiled_kernel<4><<<gtiles, 256, 0, stream>>>(x, W1, a_src1, a_dst1, HmH, As1, Ad1, N);
    agg1_kernel<<<(N + 3) / 4, 256, 0, stream>>>((const float4*)HmH, col, start, cnt,
                                                 (const float4*)As1, (const float4*)Ad1,
                                                 b1, bufB, N);

    // layer 2 (h2 reuses HmH; gemm2 reads g1 from d_out, agg2 then overwrites d_out)
    gemm_tiled_kernel<1><<<gtiles, 256, 0, stream>>>(bufB, W2, a_src2, a_dst2, HmH, As2, Ad2, N);
    agg2_kernel<<<(N + 3) / 4, 256, 0, stream>>>((const float4*)HmH, col, start, cnt,
                                                 As2, Ad2, b2, (float*)d_out, N);
}

// Round 7
// 506.812 us; speedup vs baseline: 1.6943x; 1.1972x over previous
//
#include <hip/hip_runtime.h>
#include <hip/hip_fp16.h>
#include <math.h>

#define NEG_SLOPE 0.2f

__device__ __forceinline__ float lrelu(float x) { return x >= 0.f ? x : NEG_SLOPE * x; }

// ---------------- CSR build (by dst), atomic-light ----------------
// hist_rank: per-edge rank within its dst bucket (keeps the atomic's return).
__global__ void hist_rank_kernel(const int* __restrict__ dst, int E,
                                 int* __restrict__ cnt, int* __restrict__ rank) {
    int i = blockIdx.x * blockDim.x + threadIdx.x;
    if (i < E) rank[i] = atomicAdd(&cnt[dst[i]], 1);
}

// wave-scan allocation: 1 atomic per wave
__global__ void alloc_kernel(const int* __restrict__ cnt, int N,
                             int* __restrict__ start, int* __restrict__ total) {
    int i = blockIdx.x * blockDim.x + threadIdx.x;
    int lane = threadIdx.x & 63;
    int v = (i < N) ? cnt[i] + 1 : 0;   // +1 self loop
    int incl = v;
#pragma unroll
    for (int d = 1; d < 64; d <<= 1) {
        int t = __shfl_up(incl, d);
        if (lane >= d) incl += t;
    }
    int wtot = __shfl(incl, 63);
    int base = 0;
    if (lane == 0) base = atomicAdd(total, wtot);
    base = __shfl(base, 0);
    if (i < N) start[i] = base + incl - v;
}

// atomic-free scatter: position = start[dst] + precomputed rank
__global__ void scatter_kernel(const int* __restrict__ src, const int* __restrict__ dst,
                               const int* __restrict__ rank, const int* __restrict__ cnt,
                               const int* __restrict__ start, int E, int N,
                               int* __restrict__ col) {
    int i = blockIdx.x * blockDim.x + threadIdx.x;
    if (i < E) {
        int d = dst[i];
        col[start[d] + rank[i]] = src[i];
    } else if (i < E + N) {
        int n = i - E;
        col[start[n] + cnt[n]] = n;    // self loop last in bucket
    }
}

// ---------------- Register-tiled GEMM (M x 128 @ 128 x 128) + alpha epilogue ----
// 256 threads -> 64 rows x 128 cols. Thread (tx,ty) owns 8x4 accumulators.
// Feature output written as fp16 (halves aggregation gather traffic).

template <int H>
__global__ __launch_bounds__(256) void gemm_tiled_kernel(
    const float* __restrict__ X, const float* __restrict__ W,
    const float* __restrict__ avs, const float* __restrict__ avd,
    __half* __restrict__ HmH, float* __restrict__ As, float* __restrict__ Ad, int N) {
    __shared__ float Xs[32][64];    // [k][row]
    __shared__ float Ws[32][128];   // [k][col]
    const int tid = threadIdx.x;
    const int tx = tid & 31;
    const int ty = tid >> 5;
    const int row0 = blockIdx.x * 64;

    float acc[8][4];
#pragma unroll
    for (int r = 0; r < 8; ++r)
#pragma unroll
        for (int c = 0; c < 4; ++c) acc[r][c] = 0.f;

    const float4 as_v = *(const float4*)(avs + tx * 4);
    const float4 ad_v = *(const float4*)(avd + tx * 4);

    for (int k0 = 0; k0 < 128; k0 += 32) {
#pragma unroll
        for (int i = 0; i < 2; ++i) {
            int c = tid + 256 * i;
            int r = c & 63;
            int kc = (c >> 6) << 2;
            int grow = row0 + r;
            float4 v = make_float4(0.f, 0.f, 0.f, 0.f);
            if (grow < N) v = *(const float4*)(X + (size_t)grow * 128 + k0 + kc);
            Xs[kc + 0][r] = v.x;
            Xs[kc + 1][r] = v.y;
            Xs[kc + 2][r] = v.z;
            Xs[kc + 3][r] = v.w;
        }
#pragma unroll
        for (int i = 0; i < 4; ++i) {
            int c = tid + 256 * i;
            int kk = c >> 5;
            int cc = (c & 31) << 2;
            *(float4*)(&Ws[kk][cc]) = *(const float4*)(W + (size_t)(k0 + kk) * 128 + cc);
        }
        __syncthreads();
#pragma unroll
        for (int k = 0; k < 32; ++k) {
            float4 xa = *(const float4*)(&Xs[k][ty * 8]);
            float4 xb = *(const float4*)(&Xs[k][ty * 8 + 4]);
            float4 wv = *(const float4*)(&Ws[k][tx * 4]);
            float xf[8] = {xa.x, xa.y, xa.z, xa.w, xb.x, xb.y, xb.z, xb.w};
            float wf[4] = {wv.x, wv.y, wv.z, wv.w};
#pragma unroll
            for (int r = 0; r < 8; ++r)
#pragma unroll
                for (int c = 0; c < 4; ++c) acc[r][c] += xf[r] * wf[c];
        }
        __syncthreads();
    }

#pragma unroll
    for (int r = 0; r < 8; ++r) {
        int grow = row0 + ty * 8 + r;
        if (grow >= N) continue;   // uniform across each 32-lane half
        float4 o = make_float4(acc[r][0], acc[r][1], acc[r][2], acc[r][3]);
        __half2* o2 = (__half2*)(HmH + (size_t)grow * 128 + tx * 4);
        o2[0] = __floats2half2_rn(o.x, o.y);
        o2[1] = __floats2half2_rn(o.z, o.w);
        float ps = o.x * as_v.x + o.y * as_v.y + o.z * as_v.z + o.w * as_v.w;
        float pd = o.x * ad_v.x + o.y * ad_v.y + o.z * ad_v.z + o.w * ad_v.w;
        if (H == 4) {
            ps += __shfl_xor(ps, 1); ps += __shfl_xor(ps, 2); ps += __shfl_xor(ps, 4);
            pd += __shfl_xor(pd, 1); pd += __shfl_xor(pd, 2); pd += __shfl_xor(pd, 4);
            if ((tx & 7) == 0) {
                int h = tx >> 3;
                As[(size_t)grow * 4 + h] = ps;
                Ad[(size_t)grow * 4 + h] = pd;
            }
        } else {
#pragma unroll
            for (int m = 1; m <= 16; m <<= 1) {
                ps += __shfl_xor(ps, m);
                pd += __shfl_xor(pd, m);
            }
            if (tx == 0) { As[grow] = ps; Ad[grow] = pd; }
        }
    }
}

// ---------------- Fused aggregation layer 1 (H=4, +bias, ELU) ----------------
// One wave per dst node. Lanes = 8 edge slots (qid=lane>>3) x 8 channel-pair
// groups (l7=lane&7). Lane owns chunkA = channels 8*l7..+7 (head l7>>2) and
// chunkB = channels 64+8*l7..+7 (head 2+(l7>>2)). 8 gathers in flight/wave.
// Softmax without max-subtraction (logits O(+-6)); normalization applied after
// accumulation (linear).

__global__ __launch_bounds__(256) void agg1_kernel(
    const float4* __restrict__ Hm4,     // fp16 feature rows viewed as 16 x float4
    const int* __restrict__ col,
    const int* __restrict__ start, const int* __restrict__ cnt,
    const float4* __restrict__ As4, const float4* __restrict__ Ad4,
    const float* __restrict__ bias, float* __restrict__ G, int N) {
    const int lane = threadIdx.x & 63;
    const int node = (blockIdx.x * 256 + threadIdx.x) >> 6;
    if (node >= N) return;
    const int qid = lane >> 3;
    const int l7 = lane & 7;
    const int hA = l7 >> 2;            // chunkA head: 0/1; chunkB head: 2+hA
    const int s = start[node];
    const int e_end = s + cnt[node] + 1;
    const float4 ad4 = Ad4[node];
    const float adA = hA == 0 ? ad4.x : ad4.y;
    const float adB = hA == 0 ? ad4.z : ad4.w;

    float accA[8], accB[8];
#pragma unroll
    for (int c = 0; c < 8; ++c) { accA[c] = 0.f; accB[c] = 0.f; }
    float dA = 0.f, dB = 0.f;

    for (int j = s; j < e_end; j += 8) {
        const int jj = j + qid;
        const bool act = jj < e_end;
        const int u = act ? col[jj] : 0;
        const float4 a4 = As4[u];
        const float aA = hA == 0 ? a4.x : a4.y;
        const float aB = hA == 0 ? a4.z : a4.w;
        const float pA = act ? __expf(lrelu(aA + adA)) : 0.f;
        const float pB = act ? __expf(lrelu(aB + adB)) : 0.f;
        dA += pA; dB += pB;
        const float4 hvA = Hm4[(size_t)u * 16 + l7];
        const float4 hvB = Hm4[(size_t)u * 16 + 8 + l7];
        const __half2* cA = (const __half2*)&hvA;
        const __half2* cB = (const __half2*)&hvB;
#pragma unroll
        for (int q = 0; q < 4; ++q) {
            float2 fa = __half22float2(cA[q]);
            float2 fb = __half22float2(cB[q]);
            accA[2 * q] += pA * fa.x; accA[2 * q + 1] += pA * fa.y;
            accB[2 * q] += pB * fb.x; accB[2 * q + 1] += pB * fb.y;
        }
    }

    // denom: lanes sharing a head differ in bits {0,1} (l7) and {3,4,5} (qid);
    // each edge's p appears in 4 lanes -> scale by 1/4.
#pragma unroll
    for (int m = 0; m < 5; ++m) {
        const int msk = (int[]){1, 2, 8, 16, 32}[m];
        dA += __shfl_xor(dA, msk);
        dB += __shfl_xor(dB, msk);
    }
    const float ivA = 1.f / (dA * 0.25f + 1e-16f);
    const float ivB = 1.f / (dB * 0.25f + 1e-16f);

    // combine the 8 edge slots' partial feature sums
#pragma unroll
    for (int c = 0; c < 8; ++c) {
        accA[c] += __shfl_xor(accA[c], 8);
        accA[c] += __shfl_xor(accA[c], 16);
        accA[c] += __shfl_xor(accA[c], 32);
        accB[c] += __shfl_xor(accB[c], 8);
        accB[c] += __shfl_xor(accB[c], 16);
        accB[c] += __shfl_xor(accB[c], 32);
    }

    if (qid == 0) {
        const float4* b4 = (const float4*)bias;
        const float4 bA0 = b4[2 * l7],      bA1 = b4[2 * l7 + 1];
        const float4 bB0 = b4[16 + 2 * l7], bB1 = b4[17 + 2 * l7];
        float o[16];
        o[0] = accA[0] * ivA + bA0.x; o[1] = accA[1] * ivA + bA0.y;
        o[2] = accA[2] * ivA + bA0.z; o[3] = accA[3] * ivA + bA0.w;
        o[4] = accA[4] * ivA + bA1.x; o[5] = accA[5] * ivA + bA1.y;
        o[6] = accA[6] * ivA + bA1.z; o[7] = accA[7] * ivA + bA1.w;
        o[8] = accB[0] * ivB + bB0.x; o[9] = accB[1] * ivB + bB0.y;
        o[10] = accB[2] * ivB + bB0.z; o[11] = accB[3] * ivB + bB0.w;
        o[12] = accB[4] * ivB + bB1.x; o[13] = accB[5] * ivB + bB1.y;
        o[14] = accB[6] * ivB + bB1.z; o[15] = accB[7] * ivB + bB1.w;
#pragma unroll
        for (int c = 0; c < 16; ++c) o[c] = o[c] > 0.f ? o[c] : expm1f(o[c]);
        float4* dst = (float4*)G + (size_t)node * 32;
        dst[2 * l7]      = make_float4(o[0], o[1], o[2], o[3]);
        dst[2 * l7 + 1]  = make_float4(o[4], o[5], o[6], o[7]);
        dst[16 + 2 * l7] = make_float4(o[8], o[9], o[10], o[11]);
        dst[17 + 2 * l7] = make_float4(o[12], o[13], o[14], o[15]);
    }
}

// ---------------- Fused aggregation layer 2 (H=1, +bias) ----------------

__global__ __launch_bounds__(256) void agg2_kernel(
    const float4* __restrict__ Hm4, const int* __restrict__ col,
    const int* __restrict__ start, const int* __restrict__ cnt,
    const float* __restrict__ As, const float* __restrict__ Ad,
    const float* __restrict__ bias, float* __restrict__ Out, int N) {
    const int lane = threadIdx.x & 63;
    const int node = (blockIdx.x * 256 + threadIdx.x) >> 6;
    if (node >= N) return;
    const int qid = lane >> 3;
    const int l7 = lane & 7;
    const int s = start[node];
    const int e_end = s + cnt[node] + 1;
    const float adh = Ad[node];

    float accA[8], accB[8];
#pragma unroll
    for (int c = 0; c < 8; ++c) { accA[c] = 0.f; accB[c] = 0.f; }
    float dacc = 0.f;

    for (int j = s; j < e_end; j += 8) {
        const int jj = j + qid;
        const bool act = jj < e_end;
        const int u = act ? col[jj] : 0;
        const float p = act ? __expf(lrelu(As[u] + adh)) : 0.f;
        dacc += p;
        const float4 hvA = Hm4[(size_t)u * 16 + l7];
        const float4 hvB = Hm4[(size_t)u * 16 + 8 + l7];
        const __half2* cA = (const __half2*)&hvA;
        const __half2* cB = (const __half2*)&hvB;
#pragma unroll
        for (int q = 0; q < 4; ++q) {
            float2 fa = __half22float2(cA[q]);
            float2 fb = __half22float2(cB[q]);
            accA[2 * q] += p * fa.x; accA[2 * q + 1] += p * fa.y;
            accB[2 * q] += p * fb.x; accB[2 * q + 1] += p * fb.y;
        }
    }

    // denom: each edge's p appears in 8 lanes -> scale by 1/8
#pragma unroll
    for (int m = 1; m <= 32; m <<= 1) dacc += __shfl_xor(dacc, m);
    const float iv = 1.f / (dacc * 0.125f + 1e-16f);

#pragma unroll
    for (int c = 0; c < 8; ++c) {
        accA[c] += __shfl_xor(accA[c], 8);
        accA[c] += __shfl_xor(accA[c], 16);
        accA[c] += __shfl_xor(accA[c], 32);
        accB[c] += __shfl_xor(accB[c], 8);
        accB[c] += __shfl_xor(accB[c], 16);
        accB[c] += __shfl_xor(accB[c], 32);
    }

    if (qid == 0) {
        const float4* b4 = (const float4*)bias;
        const float4 bA0 = b4[2 * l7],      bA1 = b4[2 * l7 + 1];
        const float4 bB0 = b4[16 + 2 * l7], bB1 = b4[17 + 2 * l7];
        float4* dst = (float4*)Out + (size_t)node * 32;
        dst[2 * l7] = make_float4(accA[0] * iv + bA0.x, accA[1] * iv + bA0.y,
                                  accA[2] * iv + bA0.z, accA[3] * iv + bA0.w);
        dst[2 * l7 + 1] = make_float4(accA[4] * iv + bA1.x, accA[5] * iv + bA1.y,
                                      accA[6] * iv + bA1.z, accA[7] * iv + bA1.w);
        dst[16 + 2 * l7] = make_float4(accB[0] * iv + bB0.x, accB[1] * iv + bB0.y,
                                       accB[2] * iv + bB0.z, accB[3] * iv + bB0.w);
        dst[17 + 2 * l7] = make_float4(accB[4] * iv + bB1.x, accB[5] * iv + bB1.y,
                                       accB[6] * iv + bB1.z, accB[7] * iv + bB1.w);
    }
}

// ---------------- launch ----------------

static inline size_t align256(size_t x) { return (x + 255) & ~(size_t)255; }

extern "C" void kernel_launch(void* const* d_in, const int* in_sizes, int n_in,
                              void* d_out, int out_size, void* d_ws, size_t ws_size,
                              hipStream_t stream) {
    const float* x = (const float*)d_in[0];
    const int* edge_index = (const int*)d_in[1];
    const float* W1 = (const float*)d_in[2];
    const float* a_src1 = (const float*)d_in[3];
    const float* a_dst1 = (const float*)d_in[4];
    const float* b1 = (const float*)d_in[5];
    const float* W2 = (const float*)d_in[6];
    const float* a_src2 = (const float*)d_in[7];
    const float* a_dst2 = (const float*)d_in[8];
    const float* b2 = (const float*)d_in[9];

    const int N = in_sizes[0] / 128;
    const int E = in_sizes[1] / 2;
    const int* src = edge_index;
    const int* dst = edge_index + E;

    // workspace layout (~45 MB)
    char* ws = (char*)d_ws;
    size_t off = 0;
    int* cnt = (int*)(ws + off);   off += align256((size_t)N * 4);
    int* total = (int*)(ws + off); off += 256;
    size_t zero_bytes = off;       // cnt + total must be zeroed
    int* start = (int*)(ws + off); off += align256((size_t)N * 4);
    int* rank = (int*)(ws + off);  off += align256((size_t)E * 4);
    int* col = (int*)(ws + off);   off += align256((size_t)(E + N) * 4);
    float* As1 = (float*)(ws + off); off += align256((size_t)N * 16);
    float* Ad1 = (float*)(ws + off); off += align256((size_t)N * 16);
    float* As2 = (float*)(ws + off); off += align256((size_t)N * 4);
    float* Ad2 = (float*)(ws + off); off += align256((size_t)N * 4);
    __half* HmH = (__half*)(ws + off); off += align256((size_t)N * 128 * 2); // h1, then h2 (fp16)
    float* bufB = (float*)d_out;   // g1 = elu(out1); overwritten by agg2 at the end
    (void)ws_size;

    hipMemsetAsync(d_ws, 0, zero_bytes, stream);

    // CSR build (atomic-free scatter)
    hist_rank_kernel<<<(E + 255) / 256, 256, 0, stream>>>(dst, E, cnt, rank);
    alloc_kernel<<<(N + 255) / 256, 256, 0, stream>>>(cnt, N, start, total);
    scatter_kernel<<<(E + N + 255) / 256, 256, 0, stream>>>(src, dst, rank, cnt, start,
                                                            E, N, col);

    const int gtiles = (N + 63) / 64;

    // layer 1
    gemm_tiled_kernel<4><<<gtiles, 256, 0, stream>>>(x, W1, a_src1, a_dst1, HmH, As1, Ad1, N);
    agg1_kernel<<<(N + 3) / 4, 256, 0, stream>>>((const float4*)HmH, col, start, cnt,
                                                 (const float4*)As1, (const float4*)Ad1,
                                                 b1, bufB, N);

    // layer 2 (h2 reuses HmH; gemm2 reads g1 from d_out, agg2 then overwrites d_out)
    gemm_tiled_kernel<1><<<gtiles, 256, 0, stream>>>(bufB, W2, a_src2, a_dst2, HmH, As2, Ad2, N);
    agg2_kernel<<<(N + 3) / 4, 256, 0, stream>>>((const float4*)HmH, col, start, cnt,
                                                 As2, Ad2, b2, (float*)d_out, N);
}

// Round 8
// 496.572 us; speedup vs baseline: 1.7293x; 1.0206x over previous
//
#include <hip/hip_runtime.h>
#include <hip/hip_fp16.h>
#include <math.h>

#define NEG_SLOPE 0.2f

__device__ __forceinline__ float lrelu(float x) { return x >= 0.f ? x : NEG_SLOPE * x; }

// ---------------- CSR build (by dst), atomic-light, buckets padded to 8 ----

// pre-fill padded col with dummy node N; init dummy attention rows to -1e30
__global__ void fill_pad_kernel(int* __restrict__ col, int padTot, int N,
                                float* __restrict__ As1, float* __restrict__ As2) {
    int i = blockIdx.x * blockDim.x + threadIdx.x;
    if (i < padTot) col[i] = N;
    if (i == 0) {
        As1[4 * N + 0] = -1e30f; As1[4 * N + 1] = -1e30f;
        As1[4 * N + 2] = -1e30f; As1[4 * N + 3] = -1e30f;
        As2[N] = -1e30f;
    }
}

// hist_rank: per-edge rank within its dst bucket (keeps the atomic's return).
__global__ void hist_rank_kernel(const int* __restrict__ dst, int E,
                                 int* __restrict__ cnt, int* __restrict__ rank) {
    int i = blockIdx.x * blockDim.x + threadIdx.x;
    if (i < E) rank[i] = atomicAdd(&cnt[dst[i]], 1);
}

// wave-scan allocation of padded bucket sizes: 1 atomic per wave
__global__ void alloc_kernel(const int* __restrict__ cnt, int N,
                             int* __restrict__ start, int* __restrict__ total) {
    int i = blockIdx.x * blockDim.x + threadIdx.x;
    int lane = threadIdx.x & 63;
    int v = (i < N) ? ((cnt[i] + 1 + 7) & ~7) : 0;   // +1 self loop, pad to 8
    int incl = v;
#pragma unroll
    for (int d = 1; d < 64; d <<= 1) {
        int t = __shfl_up(incl, d);
        if (lane >= d) incl += t;
    }
    int wtot = __shfl(incl, 63);
    int base = 0;
    if (lane == 0) base = atomicAdd(total, wtot);
    base = __shfl(base, 0);
    if (i < N) start[i] = base + incl - v;
}

// atomic-free scatter: position = start[dst] + precomputed rank
__global__ void scatter_kernel(const int* __restrict__ src, const int* __restrict__ dst,
                               const int* __restrict__ rank, const int* __restrict__ cnt,
                               const int* __restrict__ start, int E, int N,
                               int* __restrict__ col) {
    int i = blockIdx.x * blockDim.x + threadIdx.x;
    if (i < E) {
        int d = dst[i];
        col[start[d] + rank[i]] = src[i];
    } else if (i < E + N) {
        int n = i - E;
        col[start[n] + cnt[n]] = n;    // self loop after real edges
    }
}

// ---------------- Register-tiled GEMM (M x 128 @ 128 x 128) + alpha epilogue ----
// 256 threads -> 64 rows x 128 cols. Thread (tx,ty) owns 8x4 accumulators.
// Feature output written as fp16 (halves aggregation gather traffic).

template <int H>
__global__ __launch_bounds__(256) void gemm_tiled_kernel(
    const float* __restrict__ X, const float* __restrict__ W,
    const float* __restrict__ avs, const float* __restrict__ avd,
    __half* __restrict__ HmH, float* __restrict__ As, float* __restrict__ Ad, int N) {
    __shared__ float Xs[32][64];    // [k][row]
    __shared__ float Ws[32][128];   // [k][col]
    const int tid = threadIdx.x;
    const int tx = tid & 31;
    const int ty = tid >> 5;
    const int row0 = blockIdx.x * 64;

    float acc[8][4];
#pragma unroll
    for (int r = 0; r < 8; ++r)
#pragma unroll
        for (int c = 0; c < 4; ++c) acc[r][c] = 0.f;

    const float4 as_v = *(const float4*)(avs + tx * 4);
    const float4 ad_v = *(const float4*)(avd + tx * 4);

    for (int k0 = 0; k0 < 128; k0 += 32) {
#pragma unroll
        for (int i = 0; i < 2; ++i) {
            int c = tid + 256 * i;
            int r = c & 63;
            int kc = (c >> 6) << 2;
            int grow = row0 + r;
            float4 v = make_float4(0.f, 0.f, 0.f, 0.f);
            if (grow < N) v = *(const float4*)(X + (size_t)grow * 128 + k0 + kc);
            Xs[kc + 0][r] = v.x;
            Xs[kc + 1][r] = v.y;
            Xs[kc + 2][r] = v.z;
            Xs[kc + 3][r] = v.w;
        }
#pragma unroll
        for (int i = 0; i < 4; ++i) {
            int c = tid + 256 * i;
            int kk = c >> 5;
            int cc = (c & 31) << 2;
            *(float4*)(&Ws[kk][cc]) = *(const float4*)(W + (size_t)(k0 + kk) * 128 + cc);
        }
        __syncthreads();
#pragma unroll
        for (int k = 0; k < 32; ++k) {
            float4 xa = *(const float4*)(&Xs[k][ty * 8]);
            float4 xb = *(const float4*)(&Xs[k][ty * 8 + 4]);
            float4 wv = *(const float4*)(&Ws[k][tx * 4]);
            float xf[8] = {xa.x, xa.y, xa.z, xa.w, xb.x, xb.y, xb.z, xb.w};
            float wf[4] = {wv.x, wv.y, wv.z, wv.w};
#pragma unroll
            for (int r = 0; r < 8; ++r)
#pragma unroll
                for (int c = 0; c < 4; ++c) acc[r][c] += xf[r] * wf[c];
        }
        __syncthreads();
    }

#pragma unroll
    for (int r = 0; r < 8; ++r) {
        int grow = row0 + ty * 8 + r;
        if (grow >= N) continue;   // uniform across each 32-lane half
        float4 o = make_float4(acc[r][0], acc[r][1], acc[r][2], acc[r][3]);
        __half2* o2 = (__half2*)(HmH + (size_t)grow * 128 + tx * 4);
        o2[0] = __floats2half2_rn(o.x, o.y);
        o2[1] = __floats2half2_rn(o.z, o.w);
        float ps = o.x * as_v.x + o.y * as_v.y + o.z * as_v.z + o.w * as_v.w;
        float pd = o.x * ad_v.x + o.y * ad_v.y + o.z * ad_v.z + o.w * ad_v.w;
        if (H == 4) {
            ps += __shfl_xor(ps, 1); ps += __shfl_xor(ps, 2); ps += __shfl_xor(ps, 4);
            pd += __shfl_xor(pd, 1); pd += __shfl_xor(pd, 2); pd += __shfl_xor(pd, 4);
            if ((tx & 7) == 0) {
                int h = tx >> 3;
                As[(size_t)grow * 4 + h] = ps;
                Ad[(size_t)grow * 4 + h] = pd;
            }
        } else {
#pragma unroll
            for (int m = 1; m <= 16; m <<= 1) {
                ps += __shfl_xor(ps, m);
                pd += __shfl_xor(pd, m);
            }
            if (tx == 0) { As[grow] = ps; Ad[grow] = pd; }
        }
    }
}

// ---------------- Fused aggregation layer 1 (H=4, +bias, ELU) ----------------
// One wave per dst node. Lanes = 8 edge slots (qid=lane>>3) x 8 channel-pair
// groups (l7=lane&7). Lane owns chunkA = channels 8*l7..+7 (head l7>>2) and
// chunkB = channels 64+8*l7..+7 (head 2+(l7>>2)).
// Buckets padded to x8 with dummy node N (As[N]=-1e30 -> p=0): no tail masking.
// Softmax without max-subtraction; normalization applied after accumulation.

__global__ __launch_bounds__(256) void agg1_kernel(
    const float4* __restrict__ Hm4,     // fp16 feature rows viewed as 16 x float4
    const int* __restrict__ col,
    const int* __restrict__ start, const int* __restrict__ cnt,
    const float4* __restrict__ As4, const float4* __restrict__ Ad4,
    const float* __restrict__ bias, float* __restrict__ G, int N) {
    const int lane = threadIdx.x & 63;
    const int node = (blockIdx.x * 256 + threadIdx.x) >> 6;
    if (node >= N) return;
    const int qid = lane >> 3;
    const int l7 = lane & 7;
    const int hA = l7 >> 2;            // chunkA head: 0/1; chunkB head: 2+hA
    const int s = start[node];
    const int len = (cnt[node] + 1 + 7) & ~7;
    const float4 ad4 = Ad4[node];
    const float adA = hA == 0 ? ad4.x : ad4.y;
    const float adB = hA == 0 ? ad4.z : ad4.w;

    float accA[8], accB[8];
#pragma unroll
    for (int c = 0; c < 8; ++c) { accA[c] = 0.f; accB[c] = 0.f; }
    float dA = 0.f, dB = 0.f;

    for (int j = s + qid; j < s + len; j += 8) {
        const int u = col[j];
        const float4 a4 = As4[u];
        const float pA = __expf(lrelu((hA == 0 ? a4.x : a4.y) + adA));
        const float pB = __expf(lrelu((hA == 0 ? a4.z : a4.w) + adB));
        dA += pA; dB += pB;
        union { float4 f4; __half h[8]; } uA, uB;
        uA.f4 = Hm4[(size_t)u * 16 + l7];
        uB.f4 = Hm4[(size_t)u * 16 + 8 + l7];
#pragma unroll
        for (int c = 0; c < 8; ++c) {
            accA[c] = fmaf(__half2float(uA.h[c]), pA, accA[c]);   // v_fma_mix
            accB[c] = fmaf(__half2float(uB.h[c]), pB, accB[c]);
        }
    }

    // denom: lanes sharing a head differ in bits {0,1} (l7) and {3,4,5} (qid);
    // each edge's p appears in 4 lanes -> scale by 1/4.
    dA += __shfl_xor(dA, 1); dB += __shfl_xor(dB, 1);
    dA += __shfl_xor(dA, 2); dB += __shfl_xor(dB, 2);
    dA += __shfl_xor(dA, 8); dB += __shfl_xor(dB, 8);
    dA += __shfl_xor(dA, 16); dB += __shfl_xor(dB, 16);
    dA += __shfl_xor(dA, 32); dB += __shfl_xor(dB, 32);
    const float ivA = 1.f / (dA * 0.25f + 1e-16f);
    const float ivB = 1.f / (dB * 0.25f + 1e-16f);

    // combine the 8 edge slots' partial feature sums
#pragma unroll
    for (int c = 0; c < 8; ++c) {
        accA[c] += __shfl_xor(accA[c], 8);
        accA[c] += __shfl_xor(accA[c], 16);
        accA[c] += __shfl_xor(accA[c], 32);
        accB[c] += __shfl_xor(accB[c], 8);
        accB[c] += __shfl_xor(accB[c], 16);
        accB[c] += __shfl_xor(accB[c], 32);
    }

    if (qid == 0) {
        const float4* b4 = (const float4*)bias;
        const float4 bA0 = b4[2 * l7],      bA1 = b4[2 * l7 + 1];
        const float4 bB0 = b4[16 + 2 * l7], bB1 = b4[17 + 2 * l7];
        float o[16];
        o[0] = accA[0] * ivA + bA0.x; o[1] = accA[1] * ivA + bA0.y;
        o[2] = accA[2] * ivA + bA0.z; o[3] = accA[3] * ivA + bA0.w;
        o[4] = accA[4] * ivA + bA1.x; o[5] = accA[5] * ivA + bA1.y;
        o[6] = accA[6] * ivA + bA1.z; o[7] = accA[7] * ivA + bA1.w;
        o[8] = accB[0] * ivB + bB0.x; o[9] = accB[1] * ivB + bB0.y;
        o[10] = accB[2] * ivB + bB0.z; o[11] = accB[3] * ivB + bB0.w;
        o[12] = accB[4] * ivB + bB1.x; o[13] = accB[5] * ivB + bB1.y;
        o[14] = accB[6] * ivB + bB1.z; o[15] = accB[7] * ivB + bB1.w;
#pragma unroll
        for (int c = 0; c < 16; ++c) o[c] = o[c] > 0.f ? o[c] : expm1f(o[c]);
        float4* dst = (float4*)G + (size_t)node * 32;
        dst[2 * l7]      = make_float4(o[0], o[1], o[2], o[3]);
        dst[2 * l7 + 1]  = make_float4(o[4], o[5], o[6], o[7]);
        dst[16 + 2 * l7] = make_float4(o[8], o[9], o[10], o[11]);
        dst[17 + 2 * l7] = make_float4(o[12], o[13], o[14], o[15]);
    }
}

// ---------------- Fused aggregation layer 2 (H=1, +bias) ----------------

__global__ __launch_bounds__(256) void agg2_kernel(
    const float4* __restrict__ Hm4, const int* __restrict__ col,
    const int* __restrict__ start, const int* __restrict__ cnt,
    const float* __restrict__ As, const float* __restrict__ Ad,
    const float* __restrict__ bias, float* __restrict__ Out, int N) {
    const int lane = threadIdx.x & 63;
    const int node = (blockIdx.x * 256 + threadIdx.x) >> 6;
    if (node >= N) return;
    const int qid = lane >> 3;
    const int l7 = lane & 7;
    const int s = start[node];
    const int len = (cnt[node] + 1 + 7) & ~7;
    const float adh = Ad[node];

    float accA[8], accB[8];
#pragma unroll
    for (int c = 0; c < 8; ++c) { accA[c] = 0.f; accB[c] = 0.f; }
    float dacc = 0.f;

    for (int j = s + qid; j < s + len; j += 8) {
        const int u = col[j];
        const float p = __expf(lrelu(As[u] + adh));
        dacc += p;
        union { float4 f4; __half h[8]; } uA, uB;
        uA.f4 = Hm4[(size_t)u * 16 + l7];
        uB.f4 = Hm4[(size_t)u * 16 + 8 + l7];
#pragma unroll
        for (int c = 0; c < 8; ++c) {
            accA[c] = fmaf(__half2float(uA.h[c]), p, accA[c]);   // v_fma_mix
            accB[c] = fmaf(__half2float(uB.h[c]), p, accB[c]);
        }
    }

    // denom: each edge's p appears in 8 lanes -> scale by 1/8
#pragma unroll
    for (int m = 1; m <= 32; m <<= 1) dacc += __shfl_xor(dacc, m);
    const float iv = 1.f / (dacc * 0.125f + 1e-16f);

#pragma unroll
    for (int c = 0; c < 8; ++c) {
        accA[c] += __shfl_xor(accA[c], 8);
        accA[c] += __shfl_xor(accA[c], 16);
        accA[c] += __shfl_xor(accA[c], 32);
        accB[c] += __shfl_xor(accB[c], 8);
        accB[c] += __shfl_xor(accB[c], 16);
        accB[c] += __shfl_xor(accB[c], 32);
    }

    if (qid == 0) {
        const float4* b4 = (const float4*)bias;
        const float4 bA0 = b4[2 * l7],      bA1 = b4[2 * l7 + 1];
        const float4 bB0 = b4[16 + 2 * l7], bB1 = b4[17 + 2 * l7];
        float4* dst = (float4*)Out + (size_t)node * 32;
        dst[2 * l7] = make_float4(accA[0] * iv + bA0.x, accA[1] * iv + bA0.y,
                                  accA[2] * iv + bA0.z, accA[3] * iv + bA0.w);
        dst[2 * l7 + 1] = make_float4(accA[4] * iv + bA1.x, accA[5] * iv + bA1.y,
                                      accA[6] * iv + bA1.z, accA[7] * iv + bA1.w);
        dst[16 + 2 * l7] = make_float4(accB[0] * iv + bB0.x, accB[1] * iv + bB0.y,
                                       accB[2] * iv + bB0.z, accB[3] * iv + bB0.w);
        dst[17 + 2 * l7] = make_float4(accB[4] * iv + bB1.x, accB[5] * iv + bB1.y,
                                       accB[6] * iv + bB1.z, accB[7] * iv + bB1.w);
    }
}

// ---------------- launch ----------------

static inline size_t align256(size_t x) { return (x + 255) & ~(size_t)255; }

extern "C" void kernel_launch(void* const* d_in, const int* in_sizes, int n_in,
                              void* d_out, int out_size, void* d_ws, size_t ws_size,
                              hipStream_t stream) {
    const float* x = (const float*)d_in[0];
    const int* edge_index = (const int*)d_in[1];
    const float* W1 = (const float*)d_in[2];
    const float* a_src1 = (const float*)d_in[3];
    const float* a_dst1 = (const float*)d_in[4];
    const float* b1 = (const float*)d_in[5];
    const float* W2 = (const float*)d_in[6];
    const float* a_src2 = (const float*)d_in[7];
    const float* a_dst2 = (const float*)d_in[8];
    const float* b2 = (const float*)d_in[9];

    const int N = in_sizes[0] / 128;
    const int E = in_sizes[1] / 2;
    const int* src = edge_index;
    const int* dst = edge_index + E;
    const int padTot = E + 8 * N;      // upper bound on padded col size

    // workspace layout (~50 MB)
    char* ws = (char*)d_ws;
    size_t off = 0;
    int* cnt = (int*)(ws + off);   off += align256((size_t)N * 4);
    int* total = (int*)(ws + off); off += 256;
    size_t zero_bytes = off;       // cnt + total must be zeroed
    int* start = (int*)(ws + off); off += align256((size_t)N * 4);
    int* rank = (int*)(ws + off);  off += align256((size_t)E * 4);
    int* col = (int*)(ws + off);   off += align256((size_t)padTot * 4);
    float* As1 = (float*)(ws + off); off += align256((size_t)(N + 1) * 16);
    float* Ad1 = (float*)(ws + off); off += align256((size_t)N * 16);
    float* As2 = (float*)(ws + off); off += align256((size_t)(N + 1) * 4);
    float* Ad2 = (float*)(ws + off); off += align256((size_t)N * 4);
    __half* HmH = (__half*)(ws + off); off += align256((size_t)(N + 1) * 128 * 2); // fp16 h1/h2
    float* bufB = (float*)d_out;   // g1 = elu(out1); overwritten by agg2 at the end
    (void)ws_size;

    hipMemsetAsync(d_ws, 0, zero_bytes, stream);

    // CSR build (atomic-free scatter, buckets padded to 8 with dummy node N)
    fill_pad_kernel<<<(padTot + 255) / 256, 256, 0, stream>>>(col, padTot, N, As1, As2);
    hist_rank_kernel<<<(E + 255) / 256, 256, 0, stream>>>(dst, E, cnt, rank);
    alloc_kernel<<<(N + 255) / 256, 256, 0, stream>>>(cnt, N, start, total);
    scatter_kernel<<<(E + N + 255) / 256, 256, 0, stream>>>(src, dst, rank, cnt, start,
                                                            E, N, col);

    const int gtiles = (N + 63) / 64;

    // layer 1
    gemm_tiled_kernel<4><<<gtiles, 256, 0, stream>>>(x, W1, a_src1, a_dst1, HmH, As1, Ad1, N);
    agg1_kernel<<<(N + 3) / 4, 256, 0, stream>>>((const float4*)HmH, col, start, cnt,
                                                 (const float4*)As1, (const float4*)Ad1,
                                                 b1, bufB, N);

    // layer 2 (h2 reuses HmH; gemm2 reads g1 from d_out, agg2 then overwrites d_out)
    gemm_tiled_kernel<1><<<gtiles, 256, 0, stream>>>(bufB, W2, a_src2, a_dst2, HmH, As2, Ad2, N);
    agg2_kernel<<<(N + 3) / 4, 256, 0, stream>>>((const float4*)HmH, col, start, cnt,
                                                 As2, Ad2, b2, (float*)d_out, N);
}